// Round 1
// baseline (4396.783 us; speedup 1.0000x reference)
//
#include <hip/hip_runtime.h>

#define BM 64
#define BN 64
#define BK 16

// ---------------- zero fill (float4 granularity) ----------------
__global__ __launch_bounds__(256) void zero_f(float* __restrict__ p, long n4) {
    long i = (long)blockIdx.x * blockDim.x + threadIdx.x;
    long stride = (long)gridDim.x * blockDim.x;
    float4 z = make_float4(0.f, 0.f, 0.f, 0.f);
    for (; i < n4; i += stride) reinterpret_cast<float4*>(p)[i] = z;
}

// ---------------- tiled f32 GEMM: C = act(A) @ B + bias ----------------
// A: [M,K] row-major, B: [K,N] row-major, C: [M,N]. RELU_A applies relu on A read.
template <bool RELU_A, bool GUARD_N>
__global__ __launch_bounds__(256) void gemm_bias(const float* __restrict__ A,
                                                 const float* __restrict__ B,
                                                 const float* __restrict__ bias,
                                                 float* __restrict__ C,
                                                 int M, int N, int K) {
    __shared__ float As[BK][BM];  // [k][m]
    __shared__ float Bs[BK][BN];  // [k][n]
    const int tid = threadIdx.x;
    const int bm = blockIdx.x * BM;
    const int bn = blockIdx.y * BN;
    const int ty = tid >> 4;        // 0..15 -> rows ty*4..+3
    const int tx = tid & 15;        // 0..15 -> cols tx*4..+3
    const int arow = tid >> 2;      // 0..63
    const int acol = (tid & 3) << 2;
    const int brow = tid >> 4;      // 0..15
    const int bcol = (tid & 15) << 2;

    float acc[4][4] = {};

    for (int k0 = 0; k0 < K; k0 += BK) {
        // A tile: 64 rows x 16 k  (float4 per thread, transposed into LDS)
        float4 av = make_float4(0.f, 0.f, 0.f, 0.f);
        int gr = bm + arow;
        if (gr < M) av = *reinterpret_cast<const float4*>(&A[(long)gr * K + k0 + acol]);
        if (RELU_A) {
            av.x = fmaxf(av.x, 0.f); av.y = fmaxf(av.y, 0.f);
            av.z = fmaxf(av.z, 0.f); av.w = fmaxf(av.w, 0.f);
        }
        As[acol + 0][arow] = av.x;
        As[acol + 1][arow] = av.y;
        As[acol + 2][arow] = av.z;
        As[acol + 3][arow] = av.w;
        // B tile: 16 k x 64 cols
        if (!GUARD_N) {
            float4 bv = *reinterpret_cast<const float4*>(&B[(long)(k0 + brow) * N + bn + bcol]);
            *reinterpret_cast<float4*>(&Bs[brow][bcol]) = bv;
        } else {
            #pragma unroll
            for (int j = 0; j < 4; ++j) {
                int gc = bn + bcol + j;
                Bs[brow][bcol + j] = (gc < N) ? B[(long)(k0 + brow) * N + gc] : 0.f;
            }
        }
        __syncthreads();
        #pragma unroll
        for (int k = 0; k < BK; ++k) {
            float a[4], b[4];
            #pragma unroll
            for (int i = 0; i < 4; ++i) a[i] = As[k][ty * 4 + i];
            #pragma unroll
            for (int j = 0; j < 4; ++j) b[j] = Bs[k][tx * 4 + j];
            #pragma unroll
            for (int i = 0; i < 4; ++i)
                #pragma unroll
                for (int j = 0; j < 4; ++j) acc[i][j] += a[i] * b[j];
        }
        __syncthreads();
    }

    #pragma unroll
    for (int i = 0; i < 4; ++i) {
        int r = bm + ty * 4 + i;
        if (r >= M) continue;
        #pragma unroll
        for (int j = 0; j < 4; ++j) {
            int c = bn + tx * 4 + j;
            if (!GUARD_N || c < N) C[(long)r * N + c] = acc[i][j] + bias[c];
        }
    }
}

// ---------------- edge scatter: y[dst] += h[src] * w, F == 256 ----------------
__global__ __launch_bounds__(256) void conv_scatter_v4(const float* __restrict__ h,
                                                       const int* __restrict__ src,
                                                       const int* __restrict__ dst,
                                                       const float* __restrict__ w,
                                                       float* __restrict__ y, int E) {
    long idx = (long)blockIdx.x * blockDim.x + threadIdx.x;
    long total = (long)E * 64;
    if (idx >= total) return;
    int e = (int)(idx >> 6);
    int f4 = (int)(idx & 63) << 2;
    int s = src[e], d = dst[e];
    float we = w[e];
    float4 v = *reinterpret_cast<const float4*>(&h[(long)s * 256 + f4]);
    float* yp = &y[(long)d * 256 + f4];
    atomicAdd(yp + 0, v.x * we);
    atomicAdd(yp + 1, v.y * we);
    atomicAdd(yp + 2, v.z * we);
    atomicAdd(yp + 3, v.w * we);
}

// ---------------- edge scatter generic F (<=64) ----------------
__global__ __launch_bounds__(256) void conv_scatter_gen(const float* __restrict__ h,
                                                        const int* __restrict__ src,
                                                        const int* __restrict__ dst,
                                                        const float* __restrict__ w,
                                                        float* __restrict__ y, int E, int F) {
    long idx = (long)blockIdx.x * blockDim.x + threadIdx.x;
    long total = (long)E * 64;
    if (idx >= total) return;
    int e = (int)(idx >> 6);
    int f = (int)(idx & 63);
    if (f >= F) return;
    int s = src[e], d = dst[e];
    atomicAdd(&y[(long)d * F + f], h[(long)s * F + f] * w[e]);
}

// ---------------- column mean over rows: mean_x[j] = mean(y[:, j]) ----------------
__global__ __launch_bounds__(256) void col_mean(const float* __restrict__ y,
                                                float* __restrict__ mean_x,
                                                int rows, int cols) {
    int j = blockIdx.x;
    float s = 0.f;
    for (int i = threadIdx.x; i < rows; i += blockDim.x) s += y[(long)i * cols + j];
    __shared__ float red[256];
    red[threadIdx.x] = s;
    __syncthreads();
    for (int o = 128; o > 0; o >>= 1) {
        if (threadIdx.x < o) red[threadIdx.x] += red[threadIdx.x + o];
        __syncthreads();
    }
    if (threadIdx.x == 0) mean_x[j] = red[0] / (float)rows;
}

// ---------------- reg loss: sum((u_sum[i]/n3 * h[i,j] - mean_x[j])^2) ----------------
__global__ __launch_bounds__(256) void reg_loss_k(const float* __restrict__ h,
                                                  const float* __restrict__ u_sum,
                                                  const float* __restrict__ mean_x,
                                                  float* __restrict__ acc,
                                                  int rows, int cols, float inv_n3) {
    long total = (long)rows * cols;
    long idx = (long)blockIdx.x * blockDim.x + threadIdx.x;
    long stride = (long)gridDim.x * blockDim.x;
    float s = 0.f;
    for (long t = idx; t < total; t += stride) {
        int i = (int)(t / cols);
        int j = (int)(t - (long)i * cols);
        float mu = u_sum[i] * inv_n3;
        float d = mu * h[t] - mean_x[j];
        s += d * d;
    }
    __shared__ float red[256];
    red[threadIdx.x] = s;
    __syncthreads();
    for (int o = 128; o > 0; o >>= 1) {
        if (threadIdx.x < o) red[threadIdx.x] += red[threadIdx.x + o];
        __syncthreads();
    }
    if (threadIdx.x == 0) atomicAdd(acc, red[0]);
}

__global__ void finalize_k(float* __restrict__ out, const float* __restrict__ acc, float scale) {
    if (threadIdx.x == 0) *out = *acc * scale;
}

extern "C" void kernel_launch(void* const* d_in, const int* in_sizes, int n_in,
                              void* d_out, int out_size, void* d_ws, size_t ws_size,
                              hipStream_t stream) {
    const float* x   = (const float*)d_in[0];
    const float* W1  = (const float*)d_in[1];
    const float* b1  = (const float*)d_in[2];
    const float* W2  = (const float*)d_in[3];
    const float* b2  = (const float*)d_in[4];
    const float* W3  = (const float*)d_in[5];
    const float* b3  = (const float*)d_in[6];
    const float* ew1 = (const float*)d_in[7];
    const float* ew2 = (const float*)d_in[8];
    const float* ew3 = (const float*)d_in[9];
    const float* u_sum = (const float*)d_in[10];
    const int* s1 = (const int*)d_in[11];
    const int* d1 = (const int*)d_in[12];
    const int* s2 = (const int*)d_in[13];
    const int* d2 = (const int*)d_in[14];
    const int* s3 = (const int*)d_in[15];
    const int* d3 = (const int*)d_in[16];

    const int K  = 256;                      // in_feats == n_hidden
    const int n0 = in_sizes[0] / K;          // 100000
    const int E1 = in_sizes[7];              // 800000
    const int E2 = in_sizes[8];              // 400000
    const int E3 = in_sizes[9];              // 200000
    const int n2 = in_sizes[10];             // 25000
    const int NC = in_sizes[5] / K;          // 47
    const int n3 = (out_size - 1) / NC;      // 12500
    const int n1 = 50000;                    // fixed by problem (device-only scalar)

    float* ws     = (float*)d_ws;
    float* bufA   = ws;                          // h1 [n0,256] -> h2 [n1,256] -> h3 [n2,NC]
    float* bufB   = ws + (long)n0 * 256;         // y1 [n1,256] -> y2 [n2,256]
    float* mean_x = bufB + (long)n1 * 256;       // [48]
    float* acc    = mean_x + 48;                 // [1]

    float* y3   = (float*)d_out;                 // [n3, NC]
    float* loss = y3 + (long)n3 * NC;            // scalar

    dim3 blk(256);

    // layer 1: h1 = x @ W1 + b1
    gemm_bias<false, false><<<dim3((n0 + BM - 1) / BM, 256 / BN), blk, 0, stream>>>(
        x, W1, b1, bufA, n0, 256, K);
    // y1 = 0; y1[d] += h1[s] * w
    zero_f<<<dim3(2048), blk, 0, stream>>>(bufB, (long)n1 * 256 / 4);
    conv_scatter_v4<<<dim3((unsigned)(((long)E1 * 64 + 255) / 256)), blk, 0, stream>>>(
        bufA, s1, d1, ew1, bufB, E1);

    // layer 2: h2 = relu(y1) @ W2 + b2
    gemm_bias<true, false><<<dim3((n1 + BM - 1) / BM, 256 / BN), blk, 0, stream>>>(
        bufB, W2, b2, bufA, n1, 256, K);
    zero_f<<<dim3(2048), blk, 0, stream>>>(bufB, (long)n2 * 256 / 4);
    conv_scatter_v4<<<dim3((unsigned)(((long)E2 * 64 + 255) / 256)), blk, 0, stream>>>(
        bufA, s2, d2, ew2, bufB, E2);

    // layer 3: h3 = relu(y2) @ W3 + b3   (N = 47, guarded)
    gemm_bias<true, true><<<dim3((n2 + BM - 1) / BM, (NC + BN - 1) / BN), blk, 0, stream>>>(
        bufB, W3, b3, bufA, n2, NC, K);

    // y3 = 0 (d_out is poisoned each run); acc = 0
    zero_f<<<dim3(1024), blk, 0, stream>>>(y3, (long)n3 * NC / 4);
    zero_f<<<dim3(1), dim3(64), 0, stream>>>(acc, 1);

    // conv3: y3[d] += h3[s] * w  (F = 47)
    conv_scatter_gen<<<dim3((unsigned)(((long)E3 * 64 + 255) / 256)), blk, 0, stream>>>(
        bufA, s3, d3, ew3, y3, E3, NC);

    // mean_x[j] = mean(y3[:, j])
    col_mean<<<dim3(NC), blk, 0, stream>>>(y3, mean_x, n3, NC);

    // reg_loss = sum((u_sum/n3 * h3 - mean_x)^2) / (n2 * NC)
    reg_loss_k<<<dim3(2048), blk, 0, stream>>>(bufA, u_sum, mean_x, acc, n2, NC, 1.0f / (float)n3);
    finalize_k<<<dim3(1), dim3(1), 0, stream>>>(loss, acc, 1.0f / ((float)n2 * (float)NC));
}

// Round 2
// 777.030 us; speedup vs baseline: 5.6584x; 5.6584x over previous
//
#include <hip/hip_runtime.h>

#define BM 64
#define BN 64
#define BK 16

// ---------------- small utility kernels ----------------
__global__ __launch_bounds__(256) void zero_i(int* __restrict__ p, int n) {
    int i = blockIdx.x * 256 + threadIdx.x;
    int st = gridDim.x * 256;
    for (; i < n; i += st) p[i] = 0;
}

__global__ __launch_bounds__(256) void copy_i(const int* __restrict__ a, int* __restrict__ b, int n) {
    int i = blockIdx.x * 256 + threadIdx.x;
    int st = gridDim.x * 256;
    for (; i < n; i += st) b[i] = a[i];
}

// histogram of dst + per-dst weight rowsum
__global__ __launch_bounds__(256) void hist_k(const int* __restrict__ dst,
                                              const float* __restrict__ w, int E,
                                              int* __restrict__ cnt, float* __restrict__ rw) {
    int i = blockIdx.x * 256 + threadIdx.x;
    int st = gridDim.x * 256;
    for (; i < E; i += st) {
        int d = dst[i];
        atomicAdd(&cnt[d], 1);
        if (rw) atomicAdd(&rw[d], w[i]);
    }
}

// single-block exclusive scan (wave shuffles), n up to ~64k; writes off[0..n]
__global__ __launch_bounds__(1024) void scan_excl(const int* __restrict__ cnt,
                                                  int* __restrict__ off, int n) {
    __shared__ int wsum[16];
    __shared__ int carry_s;
    if (threadIdx.x == 0) carry_s = 0;
    __syncthreads();
    const int lane = threadIdx.x & 63;
    const int wid = threadIdx.x >> 6;
    for (int base = 0; base < n; base += 1024) {
        int i = base + threadIdx.x;
        int v = (i < n) ? cnt[i] : 0;
        // inclusive scan within wave
        int s = v;
        #pragma unroll
        for (int o = 1; o < 64; o <<= 1) {
            int t = __shfl_up(s, o, 64);
            if (lane >= o) s += t;
        }
        if (lane == 63) wsum[wid] = s;
        __syncthreads();
        if (wid == 0 && lane < 16) {
            int t = wsum[lane];
            #pragma unroll
            for (int o = 1; o < 16; o <<= 1) {
                int u = __shfl_up(t, o, 64);
                if (lane >= o) t += u;
            }
            wsum[lane] = t;  // inclusive wave-prefix
        }
        __syncthreads();
        int woff = (wid > 0) ? wsum[wid - 1] : 0;
        int carry = carry_s;
        if (i < n) off[i] = carry + woff + s - v;  // exclusive
        __syncthreads();
        if (threadIdx.x == 1023) carry_s = carry + wsum[15];
        __syncthreads();
    }
    if (threadIdx.x == 0) off[n] = carry_s;
}

// scatter edges into CSR slots
__global__ __launch_bounds__(256) void fill_k(const int* __restrict__ src,
                                              const int* __restrict__ dst,
                                              const float* __restrict__ w, int E,
                                              int* __restrict__ cur,
                                              int* __restrict__ csr_s, float* __restrict__ csr_w) {
    int i = blockIdx.x * 256 + threadIdx.x;
    int st = gridDim.x * 256;
    for (; i < E; i += st) {
        int p = atomicAdd(&cur[dst[i]], 1);
        csr_s[p] = src[i];
        csr_w[p] = w[i];
    }
}

// ---------------- gather aggregation, F == 256 (one wave per dst row) ----------------
__global__ __launch_bounds__(256) void gather_f4(const float* __restrict__ h,
                                                 const int* __restrict__ off,
                                                 const int* __restrict__ csr_s,
                                                 const float* __restrict__ csr_w,
                                                 float* __restrict__ y, int n_dst) {
    int d = blockIdx.x * 4 + (threadIdx.x >> 6);
    if (d >= n_dst) return;
    int lane = threadIdx.x & 63;
    int i0 = off[d], i1 = off[d + 1];
    float4 acc = make_float4(0.f, 0.f, 0.f, 0.f);
    for (int i = i0; i < i1; ++i) {
        int s = csr_s[i];
        float wv = csr_w[i];
        float4 v = *reinterpret_cast<const float4*>(&h[(long)s * 256 + lane * 4]);
        acc.x += wv * v.x; acc.y += wv * v.y; acc.z += wv * v.z; acc.w += wv * v.w;
    }
    *reinterpret_cast<float4*>(&y[(long)d * 256 + lane * 4]) = acc;
}

// ---------------- gather aggregation, small F (<=64), one wave per dst row ----------------
__global__ __launch_bounds__(256) void gather_small(const float* __restrict__ h,
                                                    const int* __restrict__ off,
                                                    const int* __restrict__ csr_s,
                                                    const float* __restrict__ csr_w,
                                                    float* __restrict__ y, int n_dst, int F) {
    int d = blockIdx.x * 4 + (threadIdx.x >> 6);
    if (d >= n_dst) return;
    int lane = threadIdx.x & 63;
    int i0 = off[d], i1 = off[d + 1];
    float acc = 0.f;
    for (int i = i0; i < i1; ++i) {
        int s = csr_s[i];
        float wv = csr_w[i];
        if (lane < F) acc += wv * h[(long)s * F + lane];
    }
    if (lane < F) y[(long)d * F + lane] = acc;
}

// ---------------- tiled f32 GEMM: C = act(A @ B + rowsc⊗bias) ----------------
template <bool RELU_OUT, bool GUARD_N, bool ROW_SCALE>
__global__ __launch_bounds__(256) void gemm_bias(const float* __restrict__ A,
                                                 const float* __restrict__ B,
                                                 const float* __restrict__ bias,
                                                 const float* __restrict__ rowsc,
                                                 float* __restrict__ C,
                                                 int M, int N, int K) {
    __shared__ float As[BK][BM];
    __shared__ float Bs[BK][BN];
    const int tid = threadIdx.x;
    const int bm = blockIdx.x * BM;
    const int bn = blockIdx.y * BN;
    const int ty = tid >> 4;
    const int tx = tid & 15;
    const int arow = tid >> 2;
    const int acol = (tid & 3) << 2;
    const int brow = tid >> 4;
    const int bcol = (tid & 15) << 2;

    float acc[4][4] = {};

    for (int k0 = 0; k0 < K; k0 += BK) {
        float4 av = make_float4(0.f, 0.f, 0.f, 0.f);
        int gr = bm + arow;
        if (gr < M) av = *reinterpret_cast<const float4*>(&A[(long)gr * K + k0 + acol]);
        As[acol + 0][arow] = av.x;
        As[acol + 1][arow] = av.y;
        As[acol + 2][arow] = av.z;
        As[acol + 3][arow] = av.w;
        if (!GUARD_N) {
            float4 bv = *reinterpret_cast<const float4*>(&B[(long)(k0 + brow) * N + bn + bcol]);
            *reinterpret_cast<float4*>(&Bs[brow][bcol]) = bv;
        } else {
            #pragma unroll
            for (int j = 0; j < 4; ++j) {
                int gc = bn + bcol + j;
                Bs[brow][bcol + j] = (gc < N) ? B[(long)(k0 + brow) * N + gc] : 0.f;
            }
        }
        __syncthreads();
        #pragma unroll
        for (int k = 0; k < BK; ++k) {
            float a[4], b[4];
            #pragma unroll
            for (int i = 0; i < 4; ++i) a[i] = As[k][ty * 4 + i];
            #pragma unroll
            for (int j = 0; j < 4; ++j) b[j] = Bs[k][tx * 4 + j];
            #pragma unroll
            for (int i = 0; i < 4; ++i)
                #pragma unroll
                for (int j = 0; j < 4; ++j) acc[i][j] += a[i] * b[j];
        }
        __syncthreads();
    }

    #pragma unroll
    for (int i = 0; i < 4; ++i) {
        int r = bm + ty * 4 + i;
        if (r >= M) continue;
        float rs = ROW_SCALE ? rowsc[r] : 1.f;
        #pragma unroll
        for (int j = 0; j < 4; ++j) {
            int c = bn + tx * 4 + j;
            if (!GUARD_N || c < N) {
                float v = acc[i][j] + rs * bias[c];
                if (RELU_OUT) v = fmaxf(v, 0.f);
                C[(long)r * N + c] = v;
            }
        }
    }
}

// ---------------- column mean ----------------
__global__ __launch_bounds__(256) void col_mean(const float* __restrict__ y,
                                                float* __restrict__ mean_x,
                                                int rows, int cols) {
    int j = blockIdx.x;
    float s = 0.f;
    for (int i = threadIdx.x; i < rows; i += blockDim.x) s += y[(long)i * cols + j];
    __shared__ float red[256];
    red[threadIdx.x] = s;
    __syncthreads();
    for (int o = 128; o > 0; o >>= 1) {
        if (threadIdx.x < o) red[threadIdx.x] += red[threadIdx.x + o];
        __syncthreads();
    }
    if (threadIdx.x == 0) mean_x[j] = red[0] / (float)rows;
}

// ---------------- reg loss ----------------
__global__ __launch_bounds__(256) void reg_loss_k(const float* __restrict__ h,
                                                  const float* __restrict__ u_sum,
                                                  const float* __restrict__ mean_x,
                                                  float* __restrict__ acc,
                                                  int rows, int cols, float inv_n3) {
    long total = (long)rows * cols;
    long idx = (long)blockIdx.x * blockDim.x + threadIdx.x;
    long stride = (long)gridDim.x * blockDim.x;
    float s = 0.f;
    for (long t = idx; t < total; t += stride) {
        int i = (int)(t / cols);
        int j = (int)(t - (long)i * cols);
        float mu = u_sum[i] * inv_n3;
        float d = mu * h[t] - mean_x[j];
        s += d * d;
    }
    __shared__ float red[256];
    red[threadIdx.x] = s;
    __syncthreads();
    for (int o = 128; o > 0; o >>= 1) {
        if (threadIdx.x < o) red[threadIdx.x] += red[threadIdx.x + o];
        __syncthreads();
    }
    if (threadIdx.x == 0) atomicAdd(acc, red[0]);
}

__global__ void finalize_k(float* __restrict__ out, const float* __restrict__ acc, float scale) {
    if (threadIdx.x == 0) *out = *acc * scale;
}

extern "C" void kernel_launch(void* const* d_in, const int* in_sizes, int n_in,
                              void* d_out, int out_size, void* d_ws, size_t ws_size,
                              hipStream_t stream) {
    const float* x   = (const float*)d_in[0];
    const float* W1  = (const float*)d_in[1];
    const float* b1  = (const float*)d_in[2];
    const float* W2  = (const float*)d_in[3];
    const float* b2  = (const float*)d_in[4];
    const float* W3  = (const float*)d_in[5];
    const float* b3  = (const float*)d_in[6];
    const float* ew1 = (const float*)d_in[7];
    const float* ew2 = (const float*)d_in[8];
    const float* ew3 = (const float*)d_in[9];
    const float* u_sum = (const float*)d_in[10];
    const int* s1 = (const int*)d_in[11];
    const int* d1 = (const int*)d_in[12];
    const int* s2 = (const int*)d_in[13];
    const int* d2 = (const int*)d_in[14];
    const int* s3 = (const int*)d_in[15];
    const int* d3 = (const int*)d_in[16];

    const int K  = 256;
    const int E1 = in_sizes[7];              // 800000
    const int E2 = in_sizes[8];              // 400000
    const int E3 = in_sizes[9];              // 200000
    const int n2 = in_sizes[10];             // 25000
    const int NC = in_sizes[5] / K;          // 47
    const int n3 = (out_size - 1) / NC;      // 12500
    const int n1 = 50000;                    // fixed by problem

    // ---- workspace layout (4-byte words) ----
    float* ws = (float*)d_ws;
    long o = 0;
    int*   off1 = (int*)(ws + o); o += n1 + 1;
    int*   off2 = (int*)(ws + o); o += n2 + 1;
    int*   off3 = (int*)(ws + o); o += n3 + 1;
    int*   cnt  = (int*)(ws + o); o += n1;        // reused per layer
    int*   cur  = (int*)(ws + o); o += n1;        // reused per layer
    float* rw1  = ws + o; o += n1;
    float* rw2  = ws + o; o += n2;
    int*   cs1  = (int*)(ws + o); o += E1;
    float* cw1  = ws + o; o += E1;
    int*   cs2  = (int*)(ws + o); o += E2;
    float* cw2  = ws + o; o += E2;
    int*   cs3  = (int*)(ws + o); o += E3;
    float* cw3  = ws + o; o += E3;
    float* bufAgg = ws + o; o += (long)n1 * 256;  // agg1 -> agg2 -> h3
    float* bufY   = ws + o; o += (long)n1 * 256;  // y1 -> y2
    float* mean_x = ws + o; o += 64;
    float* acc    = ws + o; o += 4;

    float* y3   = (float*)d_out;             // [n3, NC]
    float* loss = y3 + (long)n3 * NC;

    dim3 blk(256);
    auto gsE = [](int E) { return dim3((unsigned)((E + 255) / 256 < 2048 ? (E + 255) / 256 : 2048)); };

    // ---- build CSR (by dst) for each layer ----
    // layer 1
    zero_i<<<dim3(64), blk, 0, stream>>>(cnt, n1);
    zero_i<<<dim3(64), blk, 0, stream>>>((int*)rw1, n1);
    hist_k<<<gsE(E1), blk, 0, stream>>>(d1, ew1, E1, cnt, rw1);
    scan_excl<<<dim3(1), dim3(1024), 0, stream>>>(cnt, off1, n1);
    copy_i<<<dim3(64), blk, 0, stream>>>(off1, cur, n1);
    fill_k<<<gsE(E1), blk, 0, stream>>>(s1, d1, ew1, E1, cur, cs1, cw1);
    // layer 2
    zero_i<<<dim3(64), blk, 0, stream>>>(cnt, n2);
    zero_i<<<dim3(64), blk, 0, stream>>>((int*)rw2, n2);
    hist_k<<<gsE(E2), blk, 0, stream>>>(d2, ew2, E2, cnt, rw2);
    scan_excl<<<dim3(1), dim3(1024), 0, stream>>>(cnt, off2, n2);
    copy_i<<<dim3(64), blk, 0, stream>>>(off2, cur, n2);
    fill_k<<<gsE(E2), blk, 0, stream>>>(s2, d2, ew2, E2, cur, cs2, cw2);
    // layer 3 (no rowsum needed: bias b3 lives inside h3)
    zero_i<<<dim3(64), blk, 0, stream>>>(cnt, n3);
    hist_k<<<gsE(E3), blk, 0, stream>>>(d3, ew3, E3, cnt, nullptr);
    scan_excl<<<dim3(1), dim3(1024), 0, stream>>>(cnt, off3, n3);
    copy_i<<<dim3(64), blk, 0, stream>>>(off3, cur, n3);
    fill_k<<<gsE(E3), blk, 0, stream>>>(s3, d3, ew3, E3, cur, cs3, cw3);

    // ---- layer 1: agg1 = S1@x ; y1 = relu(agg1@W1 + rw1⊗b1) ----
    gather_f4<<<dim3((n1 + 3) / 4), blk, 0, stream>>>(x, off1, cs1, cw1, bufAgg, n1);
    gemm_bias<true, false, true><<<dim3((n1 + BM - 1) / BM, 256 / BN), blk, 0, stream>>>(
        bufAgg, W1, b1, rw1, bufY, n1, 256, K);

    // ---- layer 2: agg2 = S2@y1 ; y2 = relu(agg2@W2 + rw2⊗b2) ----
    gather_f4<<<dim3((n2 + 3) / 4), blk, 0, stream>>>(bufY, off2, cs2, cw2, bufAgg, n2);
    gemm_bias<true, false, true><<<dim3((n2 + BM - 1) / BM, 256 / BN), blk, 0, stream>>>(
        bufAgg, W2, b2, rw2, bufY, n2, 256, K);

    // ---- layer 3: h3 = y2@W3 + b3 ; y3 = S3@h3 ----
    gemm_bias<false, true, false><<<dim3((n2 + BM - 1) / BM, (NC + BN - 1) / BN), blk, 0, stream>>>(
        bufY, W3, b3, nullptr, bufAgg, n2, NC, K);
    gather_small<<<dim3((n3 + 3) / 4), blk, 0, stream>>>(bufAgg, off3, cs3, cw3, y3, n3, NC);

    // ---- reg loss ----
    zero_i<<<dim3(1), dim3(64), 0, stream>>>((int*)acc, 1);
    col_mean<<<dim3(NC), blk, 0, stream>>>(y3, mean_x, n3, NC);
    reg_loss_k<<<dim3(1024), blk, 0, stream>>>(bufAgg, u_sum, mean_x, acc, n2, NC, 1.0f / (float)n3);
    finalize_k<<<dim3(1), dim3(1), 0, stream>>>(loss, acc, 1.0f / ((float)n2 * (float)NC));
}

// Round 3
// 634.556 us; speedup vs baseline: 6.9289x; 1.2245x over previous
//
#include <hip/hip_runtime.h>

typedef unsigned int uint;
typedef __attribute__((ext_vector_type(8))) short bf16x8;
typedef __attribute__((ext_vector_type(4))) float f32x4;

__device__ __forceinline__ float b2f(ushort h) { return __uint_as_float(((uint)h) << 16); }
__device__ __forceinline__ ushort f2b(float f) {
    uint u = __float_as_uint(f);
    return (ushort)((u + 0x7fffu + ((u >> 16) & 1u)) >> 16);
}

// ---------------- small utility kernels ----------------
__global__ __launch_bounds__(256) void zero_i(int* __restrict__ p, int n) {
    int i = blockIdx.x * 256 + threadIdx.x;
    int st = gridDim.x * 256;
    for (; i < n; i += st) p[i] = 0;
}

__global__ __launch_bounds__(256) void copy_i(const int* __restrict__ a, int* __restrict__ b, int n) {
    int i = blockIdx.x * 256 + threadIdx.x;
    int st = gridDim.x * 256;
    for (; i < n; i += st) b[i] = a[i];
}

// f32 -> bf16 (8 elems/thread)
__global__ __launch_bounds__(256) void f2b_k(const float* __restrict__ in, ushort* __restrict__ out, long n8) {
    long i = (long)blockIdx.x * 256 + threadIdx.x;
    long st = (long)gridDim.x * 256;
    for (; i < n8; i += st) {
        float4 a = reinterpret_cast<const float4*>(in)[i * 2];
        float4 b = reinterpret_cast<const float4*>(in)[i * 2 + 1];
        ushort4 o0, o1;
        o0.x = f2b(a.x); o0.y = f2b(a.y); o0.z = f2b(a.z); o0.w = f2b(a.w);
        o1.x = f2b(b.x); o1.y = f2b(b.y); o1.z = f2b(b.z); o1.w = f2b(b.w);
        reinterpret_cast<ushort4*>(out)[i * 2] = o0;
        reinterpret_cast<ushort4*>(out)[i * 2 + 1] = o1;
    }
}

// W [K][N] f32 -> Wt [N][K] bf16  (K=N=256)
__global__ __launch_bounds__(256) void wtrans(const float* __restrict__ W, ushort* __restrict__ Wt, int K, int N) {
    int k = blockIdx.x;
    int n = threadIdx.x;
    Wt[(long)n * K + k] = f2b(W[(long)k * N + n]);
}

// histogram of dst + per-dst weight rowsum
__global__ __launch_bounds__(256) void hist_k(const int* __restrict__ dst,
                                              const float* __restrict__ w, int E,
                                              int* __restrict__ cnt, float* __restrict__ rw) {
    int i = blockIdx.x * 256 + threadIdx.x;
    int st = gridDim.x * 256;
    for (; i < E; i += st) {
        int d = dst[i];
        atomicAdd(&cnt[d], 1);
        if (rw) atomicAdd(&rw[d], w[i]);
    }
}

// single-block exclusive scan
__global__ __launch_bounds__(1024) void scan_excl(const int* __restrict__ cnt,
                                                  int* __restrict__ off, int n) {
    __shared__ int wsum[16];
    __shared__ int carry_s;
    if (threadIdx.x == 0) carry_s = 0;
    __syncthreads();
    const int lane = threadIdx.x & 63;
    const int wid = threadIdx.x >> 6;
    for (int base = 0; base < n; base += 1024) {
        int i = base + threadIdx.x;
        int v = (i < n) ? cnt[i] : 0;
        int s = v;
        #pragma unroll
        for (int o = 1; o < 64; o <<= 1) {
            int t = __shfl_up(s, o, 64);
            if (lane >= o) s += t;
        }
        if (lane == 63) wsum[wid] = s;
        __syncthreads();
        if (wid == 0 && lane < 16) {
            int t = wsum[lane];
            #pragma unroll
            for (int o = 1; o < 16; o <<= 1) {
                int u = __shfl_up(t, o, 64);
                if (lane >= o) t += u;
            }
            wsum[lane] = t;
        }
        __syncthreads();
        int woff = (wid > 0) ? wsum[wid - 1] : 0;
        int carry = carry_s;
        if (i < n) off[i] = carry + woff + s - v;
        __syncthreads();
        if (threadIdx.x == 1023) carry_s = carry + wsum[15];
        __syncthreads();
    }
    if (threadIdx.x == 0) off[n] = carry_s;
}

// scatter edges into CSR slots (src + weight packed as int2)
__global__ __launch_bounds__(256) void fill_k(const int* __restrict__ src,
                                              const int* __restrict__ dst,
                                              const float* __restrict__ w, int E,
                                              int* __restrict__ cur, int2* __restrict__ csr) {
    int i = blockIdx.x * 256 + threadIdx.x;
    int st = gridDim.x * 256;
    for (; i < E; i += st) {
        int p = atomicAdd(&cur[dst[i]], 1);
        csr[p] = make_int2(src[i], __float_as_int(w[i]));
    }
}

// ---------------- gather aggregation, bf16 in/out, F == 256 ----------------
__global__ __launch_bounds__(256) void gather_b4(const ushort* __restrict__ hb,
                                                 const int* __restrict__ off,
                                                 const int2* __restrict__ csr,
                                                 ushort* __restrict__ out, int n_dst) {
    int d = blockIdx.x * 4 + (threadIdx.x >> 6);
    if (d >= n_dst) return;
    int lane = threadIdx.x & 63;
    int i0 = off[d], i1 = off[d + 1];
    float a0 = 0.f, a1 = 0.f, a2 = 0.f, a3 = 0.f;
    for (int i = i0; i < i1; ++i) {
        int2 e = csr[i];
        float wv = __int_as_float(e.y);
        ushort4 v = *reinterpret_cast<const ushort4*>(&hb[(long)e.x * 256 + lane * 4]);
        a0 += wv * b2f(v.x); a1 += wv * b2f(v.y); a2 += wv * b2f(v.z); a3 += wv * b2f(v.w);
    }
    ushort4 o;
    o.x = f2b(a0); o.y = f2b(a1); o.z = f2b(a2); o.w = f2b(a3);
    *reinterpret_cast<ushort4*>(&out[(long)d * 256 + lane * 4]) = o;
}

// ---------------- gather, small F (<=64), f32 in/out ----------------
__global__ __launch_bounds__(256) void gather_small(const float* __restrict__ h,
                                                    const int* __restrict__ off,
                                                    const int2* __restrict__ csr,
                                                    float* __restrict__ y, int n_dst, int F) {
    int d = blockIdx.x * 4 + (threadIdx.x >> 6);
    if (d >= n_dst) return;
    int lane = threadIdx.x & 63;
    int i0 = off[d], i1 = off[d + 1];
    float acc = 0.f;
    for (int i = i0; i < i1; ++i) {
        int2 e = csr[i];
        float wv = __int_as_float(e.y);
        if (lane < F) acc += wv * h[(long)e.x * F + lane];
    }
    if (lane < F) y[(long)d * F + lane] = acc;
}

// ---------------- bf16 MFMA GEMM: C = act(A @ Bt^T + rowsc⊗bias) ----------------
// A: [M][K] bf16 row-major. Bt: [N][K] bf16 (pre-transposed weight). K%32==0, N%128==0.
// Block 128x128, 4 waves (2x2), wave tile 64x64 (4x4 frags of 16x16x32).
// LDS: subtile-linear layout; staged via global_load_lds with pre-swizzled per-lane
// global addresses so ds_read_b128 of MFMA fragments is stride-1 (conflict-free).
template <bool RELU, bool OUTF32>
__global__ __launch_bounds__(256) void gemm_mfma(const ushort* __restrict__ A,
                                                 const ushort* __restrict__ Bt,
                                                 const float* __restrict__ bias,
                                                 const float* __restrict__ rowsc,
                                                 ushort* __restrict__ Cb,
                                                 float* __restrict__ Cf,
                                                 int M, int N, int K) {
    __shared__ ushort As[4096];  // 8 subtiles x (16 rows x 32 k)
    __shared__ ushort Bs[4096];
    const int tid = threadIdx.x;
    const int w = tid >> 6;
    const int lane = tid & 63;
    const int l15 = lane & 15;
    const int l4 = lane >> 4;
    const int bm = blockIdx.x * 128;
    const int bn = blockIdx.y * 128;
    const int wm = w >> 1, wn = w & 1;

    int ra0 = bm + w * 16 + l15;       if (ra0 >= M) ra0 = M - 1;
    int ra1 = bm + (w + 4) * 16 + l15; if (ra1 >= M) ra1 = M - 1;
    const ushort* pa0 = A + (long)ra0 * K + l4 * 8;
    const ushort* pa1 = A + (long)ra1 * K + l4 * 8;
    const ushort* pb0 = Bt + (long)(bn + w * 16 + l15) * K + l4 * 8;
    const ushort* pb1 = Bt + (long)(bn + (w + 4) * 16 + l15) * K + l4 * 8;

    f32x4 acc[4][4];
    f32x4 zz = {0.f, 0.f, 0.f, 0.f};
    #pragma unroll
    for (int m = 0; m < 4; ++m)
        #pragma unroll
        for (int n = 0; n < 4; ++n) acc[m][n] = zz;

    for (int k0 = 0; k0 < K; k0 += 32) {
        __builtin_amdgcn_global_load_lds((const __attribute__((address_space(1))) void*)pa0,
                                         (__attribute__((address_space(3))) void*)&As[w * 512], 16, 0, 0);
        __builtin_amdgcn_global_load_lds((const __attribute__((address_space(1))) void*)pa1,
                                         (__attribute__((address_space(3))) void*)&As[(w + 4) * 512], 16, 0, 0);
        __builtin_amdgcn_global_load_lds((const __attribute__((address_space(1))) void*)pb0,
                                         (__attribute__((address_space(3))) void*)&Bs[w * 512], 16, 0, 0);
        __builtin_amdgcn_global_load_lds((const __attribute__((address_space(1))) void*)pb1,
                                         (__attribute__((address_space(3))) void*)&Bs[(w + 4) * 512], 16, 0, 0);
        pa0 += 32; pa1 += 32; pb0 += 32; pb1 += 32;
        __syncthreads();
        bf16x8 af[4], bfr[4];
        #pragma unroll
        for (int m = 0; m < 4; ++m)
            af[m] = *reinterpret_cast<const bf16x8*>(&As[(wm * 4 + m) * 512 + lane * 8]);
        #pragma unroll
        for (int n = 0; n < 4; ++n)
            bfr[n] = *reinterpret_cast<const bf16x8*>(&Bs[(wn * 4 + n) * 512 + lane * 8]);
        #pragma unroll
        for (int m = 0; m < 4; ++m)
            #pragma unroll
            for (int n = 0; n < 4; ++n)
                acc[m][n] = __builtin_amdgcn_mfma_f32_16x16x32_bf16(af[m], bfr[n], acc[m][n], 0, 0, 0);
        __syncthreads();
    }

    const int rbase = bm + wm * 64;
    const int cbase = bn + wn * 64;
    #pragma unroll
    for (int m = 0; m < 4; ++m) {
        #pragma unroll
        for (int q = 0; q < 4; ++q) {
            int r = rbase + m * 16 + l4 * 4 + q;
            if (r >= M) continue;
            float rs = rowsc[r];
            #pragma unroll
            for (int n = 0; n < 4; ++n) {
                int c = cbase + n * 16 + l15;
                float v = acc[m][n][q] + rs * bias[c];
                if (RELU) v = fmaxf(v, 0.f);
                if (OUTF32) Cf[(long)r * N + c] = v;
                else Cb[(long)r * N + c] = f2b(v);
            }
        }
    }
}

// ---------------- f32 VALU GEMM (layer 3, N=47) ----------------
#define BM 64
#define BN 64
#define BK 16
__global__ __launch_bounds__(256) void gemm_f32(const float* __restrict__ A,
                                                const float* __restrict__ B,
                                                const float* __restrict__ bias,
                                                float* __restrict__ C,
                                                int M, int N, int K) {
    __shared__ float Asm[BK][BM];
    __shared__ float Bsm[BK][BN];
    const int tid = threadIdx.x;
    const int bm = blockIdx.x * BM;
    const int bn = blockIdx.y * BN;
    const int ty = tid >> 4;
    const int tx = tid & 15;
    const int arow = tid >> 2;
    const int acol = (tid & 3) << 2;
    const int brow = tid >> 4;
    const int bcol = (tid & 15) << 2;

    float acc[4][4] = {};

    for (int k0 = 0; k0 < K; k0 += BK) {
        float4 av = make_float4(0.f, 0.f, 0.f, 0.f);
        int gr = bm + arow;
        if (gr < M) av = *reinterpret_cast<const float4*>(&A[(long)gr * K + k0 + acol]);
        Asm[acol + 0][arow] = av.x;
        Asm[acol + 1][arow] = av.y;
        Asm[acol + 2][arow] = av.z;
        Asm[acol + 3][arow] = av.w;
        #pragma unroll
        for (int j = 0; j < 4; ++j) {
            int gc = bn + bcol + j;
            Bsm[brow][bcol + j] = (gc < N) ? B[(long)(k0 + brow) * N + gc] : 0.f;
        }
        __syncthreads();
        #pragma unroll
        for (int k = 0; k < BK; ++k) {
            float a[4], b[4];
            #pragma unroll
            for (int i = 0; i < 4; ++i) a[i] = Asm[k][ty * 4 + i];
            #pragma unroll
            for (int j = 0; j < 4; ++j) b[j] = Bsm[k][tx * 4 + j];
            #pragma unroll
            for (int i = 0; i < 4; ++i)
                #pragma unroll
                for (int j = 0; j < 4; ++j) acc[i][j] += a[i] * b[j];
        }
        __syncthreads();
    }

    #pragma unroll
    for (int i = 0; i < 4; ++i) {
        int r = bm + ty * 4 + i;
        if (r >= M) continue;
        #pragma unroll
        for (int j = 0; j < 4; ++j) {
            int c = bn + tx * 4 + j;
            if (c < N) C[(long)r * N + c] = acc[i][j] + bias[c];
        }
    }
}

// ---------------- column mean ----------------
__global__ __launch_bounds__(256) void col_mean(const float* __restrict__ y,
                                                float* __restrict__ mean_x,
                                                int rows, int cols) {
    int j = blockIdx.x;
    float s = 0.f;
    for (int i = threadIdx.x; i < rows; i += blockDim.x) s += y[(long)i * cols + j];
    __shared__ float red[256];
    red[threadIdx.x] = s;
    __syncthreads();
    for (int o = 128; o > 0; o >>= 1) {
        if (threadIdx.x < o) red[threadIdx.x] += red[threadIdx.x + o];
        __syncthreads();
    }
    if (threadIdx.x == 0) mean_x[j] = red[0] / (float)rows;
}

// ---------------- reg loss ----------------
__global__ __launch_bounds__(256) void reg_loss_k(const float* __restrict__ h,
                                                  const float* __restrict__ u_sum,
                                                  const float* __restrict__ mean_x,
                                                  float* __restrict__ acc,
                                                  int rows, int cols, float inv_n3) {
    long total = (long)rows * cols;
    long idx = (long)blockIdx.x * blockDim.x + threadIdx.x;
    long stride = (long)gridDim.x * blockDim.x;
    float s = 0.f;
    for (long t = idx; t < total; t += stride) {
        int i = (int)(t / cols);
        int j = (int)(t - (long)i * cols);
        float mu = u_sum[i] * inv_n3;
        float d = mu * h[t] - mean_x[j];
        s += d * d;
    }
    __shared__ float red[256];
    red[threadIdx.x] = s;
    __syncthreads();
    for (int o = 128; o > 0; o >>= 1) {
        if (threadIdx.x < o) red[threadIdx.x] += red[threadIdx.x + o];
        __syncthreads();
    }
    if (threadIdx.x == 0) atomicAdd(acc, red[0]);
}

__global__ void finalize_k(float* __restrict__ out, const float* __restrict__ acc, float scale) {
    if (threadIdx.x == 0) *out = *acc * scale;
}

extern "C" void kernel_launch(void* const* d_in, const int* in_sizes, int n_in,
                              void* d_out, int out_size, void* d_ws, size_t ws_size,
                              hipStream_t stream) {
    const float* x   = (const float*)d_in[0];
    const float* W1  = (const float*)d_in[1];
    const float* b1  = (const float*)d_in[2];
    const float* W2  = (const float*)d_in[3];
    const float* b2  = (const float*)d_in[4];
    const float* W3  = (const float*)d_in[5];
    const float* b3  = (const float*)d_in[6];
    const float* ew1 = (const float*)d_in[7];
    const float* ew2 = (const float*)d_in[8];
    const float* ew3 = (const float*)d_in[9];
    const float* u_sum = (const float*)d_in[10];
    const int* s1 = (const int*)d_in[11];
    const int* d1 = (const int*)d_in[12];
    const int* s2 = (const int*)d_in[13];
    const int* d2 = (const int*)d_in[14];
    const int* s3 = (const int*)d_in[15];
    const int* d3 = (const int*)d_in[16];

    const int K  = 256;
    const int n0 = in_sizes[0] / K;          // 100000
    const int E1 = in_sizes[7];              // 800000
    const int E2 = in_sizes[8];              // 400000
    const int E3 = in_sizes[9];              // 200000
    const int n2 = in_sizes[10];             // 25000
    const int NC = in_sizes[5] / K;          // 47
    const int n3 = (out_size - 1) / NC;      // 12500
    const int n1 = 50000;                    // fixed by problem

    // ---- workspace layout (4-byte words, 16B-aligned chunks) ----
    float* ws = (float*)d_ws;
    long o = 0;
    auto take = [&](long words) { float* p = ws + o; o += (words + 3) & ~3L; return p; };
    int*    off1 = (int*)take(n1 + 1);
    int*    off2 = (int*)take(n2 + 1);
    int*    off3 = (int*)take(n3 + 1);
    int*    cnt  = (int*)take(n1);
    int*    cur  = (int*)take(n1);
    float*  rw1  = take(n1);
    float*  rw2  = take(n2);
    int2*   csr1 = (int2*)take(2L * E1);
    int2*   csr2 = (int2*)take(2L * E2);
    int2*   csr3 = (int2*)take(2L * E3);
    ushort* Wt1b = (ushort*)take(256 * 256 / 2);
    ushort* Wt2b = (ushort*)take(256 * 256 / 2);
    ushort* aggb = (ushort*)take((long)n1 * 256 / 2);   // agg1 (n1 rows) then agg2 (n2 rows)
    ushort* xb   = (ushort*)take((long)n0 * 256 / 2);   // xb; later y1b (1st half) + y2f (2nd half)
    float*  h3   = take((long)n2 * 48);
    float*  mean_x = take(64);
    float*  accs   = take(4);

    ushort* y1b = xb;                                   // [n1][256] bf16 (xb dead after gather1)
    float*  y2f = (float*)(xb + (long)n1 * 256);        // [n2][256] f32

    float* y3   = (float*)d_out;                        // [n3, NC]
    float* loss = y3 + (long)n3 * NC;

    dim3 blk(256);
    auto gsE = [](int E) { return dim3((unsigned)((E + 255) / 256 < 2048 ? (E + 255) / 256 : 2048)); };

    // ---- conversions ----
    f2b_k<<<dim3(2048), blk, 0, stream>>>(x, xb, (long)n0 * 256 / 8);
    wtrans<<<dim3(256), blk, 0, stream>>>(W1, Wt1b, 256, 256);
    wtrans<<<dim3(256), blk, 0, stream>>>(W2, Wt2b, 256, 256);

    // ---- build CSR (by dst) ----
    zero_i<<<dim3(64), blk, 0, stream>>>(cnt, n1);
    zero_i<<<dim3(64), blk, 0, stream>>>((int*)rw1, n1);
    hist_k<<<gsE(E1), blk, 0, stream>>>(d1, ew1, E1, cnt, rw1);
    scan_excl<<<dim3(1), dim3(1024), 0, stream>>>(cnt, off1, n1);
    copy_i<<<dim3(64), blk, 0, stream>>>(off1, cur, n1);
    fill_k<<<gsE(E1), blk, 0, stream>>>(s1, d1, ew1, E1, cur, csr1);

    zero_i<<<dim3(64), blk, 0, stream>>>(cnt, n2);
    zero_i<<<dim3(64), blk, 0, stream>>>((int*)rw2, n2);
    hist_k<<<gsE(E2), blk, 0, stream>>>(d2, ew2, E2, cnt, rw2);
    scan_excl<<<dim3(1), dim3(1024), 0, stream>>>(cnt, off2, n2);
    copy_i<<<dim3(64), blk, 0, stream>>>(off2, cur, n2);
    fill_k<<<gsE(E2), blk, 0, stream>>>(s2, d2, ew2, E2, cur, csr2);

    zero_i<<<dim3(64), blk, 0, stream>>>(cnt, n3);
    hist_k<<<gsE(E3), blk, 0, stream>>>(d3, ew3, E3, cnt, nullptr);
    scan_excl<<<dim3(1), dim3(1024), 0, stream>>>(cnt, off3, n3);
    copy_i<<<dim3(64), blk, 0, stream>>>(off3, cur, n3);
    fill_k<<<gsE(E3), blk, 0, stream>>>(s3, d3, ew3, E3, cur, csr3);

    // ---- layer 1: agg1 = S1@xb ; y1b = relu(agg1@W1 + rw1⊗b1) ----
    gather_b4<<<dim3((n1 + 3) / 4), blk, 0, stream>>>(xb, off1, csr1, aggb, n1);
    gemm_mfma<true, false><<<dim3((n1 + 127) / 128, 2), blk, 0, stream>>>(
        aggb, Wt1b, b1, rw1, y1b, nullptr, n1, 256, K);

    // ---- layer 2: agg2 = S2@y1b ; y2f = relu(agg2@W2 + rw2⊗b2) ----
    gather_b4<<<dim3((n2 + 3) / 4), blk, 0, stream>>>(y1b, off2, csr2, aggb, n2);
    gemm_mfma<true, true><<<dim3((n2 + 127) / 128, 2), blk, 0, stream>>>(
        aggb, Wt2b, b2, rw2, nullptr, y2f, n2, 256, K);

    // ---- layer 3 (f32): h3 = y2f@W3 + b3 ; y3 = S3@h3 ----
    gemm_f32<<<dim3((n2 + BM - 1) / BM, 1), blk, 0, stream>>>(y2f, W3, b3, h3, n2, NC, K);
    gather_small<<<dim3((n3 + 3) / 4), blk, 0, stream>>>(h3, off3, csr3, y3, n3, NC);

    // ---- reg loss ----
    zero_i<<<dim3(1), dim3(64), 0, stream>>>((int*)accs, 1);
    col_mean<<<dim3(NC), blk, 0, stream>>>(y3, mean_x, n3, NC);
    reg_loss_k<<<dim3(512), blk, 0, stream>>>(h3, u_sum, mean_x, accs, n2, NC, 1.0f / (float)n3);
    finalize_k<<<dim3(1), dim3(1), 0, stream>>>(loss, accs, 1.0f / ((float)n2 * (float)NC));
}

// Round 4
// 465.873 us; speedup vs baseline: 9.4377x; 1.3621x over previous
//
#include <hip/hip_runtime.h>

typedef unsigned int uint;
typedef __attribute__((ext_vector_type(8))) short bf16x8;
typedef __attribute__((ext_vector_type(4))) float f32x4;

__device__ __forceinline__ float b2f(ushort h) { return __uint_as_float(((uint)h) << 16); }
__device__ __forceinline__ ushort f2b(float f) {
    uint u = __float_as_uint(f);
    return (ushort)((u + 0x7fffu + ((u >> 16) & 1u)) >> 16);
}

// ---------------- utility ----------------
__global__ __launch_bounds__(256) void zero_i(int* __restrict__ p, int n) {
    int i = blockIdx.x * 256 + threadIdx.x;
    int st = gridDim.x * 256;
    for (; i < n; i += st) p[i] = 0;
}

// f32 -> bf16 (8 elems/thread)
__global__ __launch_bounds__(256) void f2b_k(const float* __restrict__ in, ushort* __restrict__ out, long n8) {
    long i = (long)blockIdx.x * 256 + threadIdx.x;
    long st = (long)gridDim.x * 256;
    for (; i < n8; i += st) {
        float4 a = reinterpret_cast<const float4*>(in)[i * 2];
        float4 b = reinterpret_cast<const float4*>(in)[i * 2 + 1];
        ushort4 o0, o1;
        o0.x = f2b(a.x); o0.y = f2b(a.y); o0.z = f2b(a.z); o0.w = f2b(a.w);
        o1.x = f2b(b.x); o1.y = f2b(b.y); o1.z = f2b(b.z); o1.w = f2b(b.w);
        reinterpret_cast<ushort4*>(out)[i * 2] = o0;
        reinterpret_cast<ushort4*>(out)[i * 2 + 1] = o1;
    }
}

// all weight transposes + layer-3 zero-pad + b3 pad, one launch
__global__ __launch_bounds__(640) void wtrans_all(const float* __restrict__ W1, const float* __restrict__ W2,
                                                  const float* __restrict__ W3, const float* __restrict__ b3,
                                                  ushort* __restrict__ Wt1, ushort* __restrict__ Wt2,
                                                  ushort* __restrict__ Wt3, float* __restrict__ b3p, int NC) {
    int k = blockIdx.x;   // 0..255
    int t = threadIdx.x;
    if (t < 256) {
        Wt1[(long)t * 256 + k] = f2b(W1[(long)k * 256 + t]);
    } else if (t < 512) {
        int n = t - 256;
        Wt2[(long)n * 256 + k] = f2b(W2[(long)k * 256 + n]);
    } else {
        int n = t - 512;  // 0..127
        float v = (n < NC) ? W3[(long)k * NC + n] : 0.f;
        Wt3[(long)n * 256 + k] = f2b(v);
        if (k == 0) b3p[n] = (n < NC) ? b3[n] : 0.f;
    }
}

// fused histogram over 3 concatenated edge lists
__global__ __launch_bounds__(256) void hist_fused(const int* __restrict__ d1, const int* __restrict__ d2,
                                                  const int* __restrict__ d3,
                                                  const float* __restrict__ w1, const float* __restrict__ w2,
                                                  int E1, int E2, int E3, int n1, int n2,
                                                  int* __restrict__ cnt, float* __restrict__ rw) {
    int i = blockIdx.x * 256 + threadIdx.x;
    int st = gridDim.x * 256;
    int Et = E1 + E2 + E3;
    for (; i < Et; i += st) {
        if (i < E1) {
            int d = d1[i];
            atomicAdd(&cnt[d], 1);
            atomicAdd(&rw[d], w1[i]);
        } else if (i < E1 + E2) {
            int j = i - E1;
            int d = d2[j];
            atomicAdd(&cnt[n1 + d], 1);
            atomicAdd(&rw[n1 + d], w2[j]);
        } else {
            int j = i - E1 - E2;
            atomicAdd(&cnt[n1 + n2 + d3[j]], 1);
        }
    }
}

// ---- 3-phase parallel exclusive scan ----
// phase 1: per-1024-block local exclusive scan -> off[i]; block sum -> bsum[b]
__global__ __launch_bounds__(1024) void scan1(const int* __restrict__ cnt, int* __restrict__ off,
                                              int* __restrict__ bsum, int n) {
    __shared__ int wsum[16];
    const int lane = threadIdx.x & 63;
    const int wid = threadIdx.x >> 6;
    int i = blockIdx.x * 1024 + threadIdx.x;
    int v = (i < n) ? cnt[i] : 0;
    int s = v;
    #pragma unroll
    for (int o = 1; o < 64; o <<= 1) {
        int t = __shfl_up(s, o, 64);
        if (lane >= o) s += t;
    }
    if (lane == 63) wsum[wid] = s;
    __syncthreads();
    if (wid == 0 && lane < 16) {
        int t = wsum[lane];
        #pragma unroll
        for (int o = 1; o < 16; o <<= 1) {
            int u = __shfl_up(t, o, 64);
            if (lane >= o) t += u;
        }
        wsum[lane] = t;
    }
    __syncthreads();
    int woff = (wid > 0) ? wsum[wid - 1] : 0;
    if (i < n) off[i] = woff + s - v;
    if (threadIdx.x == 0) bsum[blockIdx.x] = wsum[15];
}

// phase 2: scan block sums (nb <= 128), write grand total to off_end, zero acc
__global__ __launch_bounds__(128) void scan2(const int* __restrict__ bsum, int* __restrict__ bbase,
                                             int nb, int* __restrict__ off_end, float* __restrict__ acc) {
    __shared__ int w0tot;
    int tid = threadIdx.x;
    int lane = tid & 63;
    int wid = tid >> 6;
    int v = (tid < nb) ? bsum[tid] : 0;
    int s = v;
    #pragma unroll
    for (int o = 1; o < 64; o <<= 1) {
        int t = __shfl_up(s, o, 64);
        if (lane >= o) s += t;
    }
    if (wid == 0 && lane == 63) w0tot = s;
    __syncthreads();
    int base = (wid == 1) ? w0tot : 0;
    if (tid < nb) bbase[tid] = base + s - v;
    if (tid == nb - 1) *off_end = base + s;
    if (tid == 0) *acc = 0.f;
}

// phase 3: add block bases; also produce cur[] copy
__global__ __launch_bounds__(256) void scan3(int* __restrict__ off, int* __restrict__ cur,
                                             const int* __restrict__ bbase, int n) {
    int i = blockIdx.x * 256 + threadIdx.x;
    int st = gridDim.x * 256;
    for (; i < n; i += st) {
        int v = off[i] + bbase[i >> 10];
        off[i] = v;
        cur[i] = v;
    }
}

// fused CSR fill
__global__ __launch_bounds__(256) void fill_fused(const int* __restrict__ s1, const int* __restrict__ d1,
                                                  const int* __restrict__ s2, const int* __restrict__ d2,
                                                  const int* __restrict__ s3, const int* __restrict__ d3,
                                                  const float* __restrict__ w1, const float* __restrict__ w2,
                                                  const float* __restrict__ w3,
                                                  int E1, int E2, int E3, int n1, int n2,
                                                  int* __restrict__ cur, int2* __restrict__ csr) {
    int i = blockIdx.x * 256 + threadIdx.x;
    int st = gridDim.x * 256;
    int Et = E1 + E2 + E3;
    for (; i < Et; i += st) {
        int sdx, base, w;
        const int j1 = i - E1, j2 = i - E1 - E2;
        if (i < E1) { sdx = s1[i]; base = d1[i]; w = __float_as_int(w1[i]); }
        else if (j2 < 0) { sdx = s2[j1]; base = n1 + d2[j1]; w = __float_as_int(w2[j1]); }
        else { sdx = s3[j2]; base = n1 + n2 + d3[j2]; w = __float_as_int(w3[j2]); }
        int p = atomicAdd(&cur[base], 1);
        csr[p] = make_int2(sdx, w);
    }
}

// ---------------- gather, bf16 in/out, F == 256, shuffle-broadcast + 8x ILP ----------------
__global__ __launch_bounds__(256) void gather_b4(const ushort* __restrict__ hb,
                                                 const int* __restrict__ off,
                                                 const int2* __restrict__ csr,
                                                 ushort* __restrict__ out, int n_dst) {
    int d = blockIdx.x * 4 + (threadIdx.x >> 6);
    if (d >= n_dst) return;
    int lane = threadIdx.x & 63;
    int i0 = off[d], i1 = off[d + 1];
    float a0 = 0.f, a1 = 0.f, a2 = 0.f, a3 = 0.f;
    for (int base = i0; base < i1; base += 64) {
        int cnt = i1 - base;
        if (cnt > 64) cnt = 64;
        int2 e = csr[base + (lane < cnt ? lane : 0)];
        int j = 0;
        for (; j + 8 <= cnt; j += 8) {
            int s[8]; float wv[8];
            #pragma unroll
            for (int u = 0; u < 8; ++u) {
                s[u] = __shfl(e.x, j + u, 64);
                wv[u] = __int_as_float(__shfl(e.y, j + u, 64));
            }
            ushort4 v[8];
            #pragma unroll
            for (int u = 0; u < 8; ++u)
                v[u] = *reinterpret_cast<const ushort4*>(&hb[(long)s[u] * 256 + lane * 4]);
            #pragma unroll
            for (int u = 0; u < 8; ++u) {
                a0 += wv[u] * b2f(v[u].x);
                a1 += wv[u] * b2f(v[u].y);
                a2 += wv[u] * b2f(v[u].z);
                a3 += wv[u] * b2f(v[u].w);
            }
        }
        for (; j < cnt; ++j) {
            int sv = __shfl(e.x, j, 64);
            float wv = __int_as_float(__shfl(e.y, j, 64));
            ushort4 v = *reinterpret_cast<const ushort4*>(&hb[(long)sv * 256 + lane * 4]);
            a0 += wv * b2f(v.x); a1 += wv * b2f(v.y); a2 += wv * b2f(v.z); a3 += wv * b2f(v.w);
        }
    }
    ushort4 o;
    o.x = f2b(a0); o.y = f2b(a1); o.z = f2b(a2); o.w = f2b(a3);
    *reinterpret_cast<ushort4*>(&out[(long)d * 256 + lane * 4]) = o;
}

// ---------------- gather, small F (<=64), f32, 4x ILP ----------------
__global__ __launch_bounds__(256) void gather_small(const float* __restrict__ h,
                                                    const int* __restrict__ off,
                                                    const int2* __restrict__ csr,
                                                    float* __restrict__ y, int n_dst, int F) {
    int d = blockIdx.x * 4 + (threadIdx.x >> 6);
    if (d >= n_dst) return;
    int lane = threadIdx.x & 63;
    int i0 = off[d], i1 = off[d + 1];
    float acc = 0.f;
    for (int base = i0; base < i1; base += 64) {
        int cnt = i1 - base;
        if (cnt > 64) cnt = 64;
        int2 e = csr[base + (lane < cnt ? lane : 0)];
        int j = 0;
        for (; j + 4 <= cnt; j += 4) {
            int s[4]; float wv[4];
            #pragma unroll
            for (int u = 0; u < 4; ++u) {
                s[u] = __shfl(e.x, j + u, 64);
                wv[u] = __int_as_float(__shfl(e.y, j + u, 64));
            }
            float v[4];
            #pragma unroll
            for (int u = 0; u < 4; ++u) v[u] = (lane < F) ? h[(long)s[u] * F + lane] : 0.f;
            #pragma unroll
            for (int u = 0; u < 4; ++u) acc += wv[u] * v[u];
        }
        for (; j < cnt; ++j) {
            int sv = __shfl(e.x, j, 64);
            float wv = __int_as_float(__shfl(e.y, j, 64));
            if (lane < F) acc += wv * h[(long)sv * F + lane];
        }
    }
    if (lane < F) y[(long)d * F + lane] = acc;
}

// ---------------- bf16 MFMA GEMM: C = act(A @ Bt^T + rowsc⊗bias) ----------------
// A: [M][K] bf16. Bt: [Npad][K] bf16 (pre-transposed, Npad%128==0). Output stride Nout.
template <bool RELU, bool OUTF32, bool ROWSC, bool GUARDN>
__global__ __launch_bounds__(256) void gemm_mfma(const ushort* __restrict__ A,
                                                 const ushort* __restrict__ Bt,
                                                 const float* __restrict__ bias,
                                                 const float* __restrict__ rowsc,
                                                 ushort* __restrict__ Cb,
                                                 float* __restrict__ Cf,
                                                 int M, int Nout, int K) {
    __shared__ ushort As[4096];
    __shared__ ushort Bs[4096];
    const int tid = threadIdx.x;
    const int w = tid >> 6;
    const int lane = tid & 63;
    const int l15 = lane & 15;
    const int l4 = lane >> 4;
    const int bm = blockIdx.x * 128;
    const int bn = blockIdx.y * 128;
    const int wm = w >> 1, wn = w & 1;

    int ra0 = bm + w * 16 + l15;       if (ra0 >= M) ra0 = M - 1;
    int ra1 = bm + (w + 4) * 16 + l15; if (ra1 >= M) ra1 = M - 1;
    const ushort* pa0 = A + (long)ra0 * K + l4 * 8;
    const ushort* pa1 = A + (long)ra1 * K + l4 * 8;
    const ushort* pb0 = Bt + (long)(bn + w * 16 + l15) * K + l4 * 8;
    const ushort* pb1 = Bt + (long)(bn + (w + 4) * 16 + l15) * K + l4 * 8;

    f32x4 acc[4][4];
    f32x4 zz = {0.f, 0.f, 0.f, 0.f};
    #pragma unroll
    for (int m = 0; m < 4; ++m)
        #pragma unroll
        for (int n = 0; n < 4; ++n) acc[m][n] = zz;

    for (int k0 = 0; k0 < K; k0 += 32) {
        __builtin_amdgcn_global_load_lds((const __attribute__((address_space(1))) void*)pa0,
                                         (__attribute__((address_space(3))) void*)&As[w * 512], 16, 0, 0);
        __builtin_amdgcn_global_load_lds((const __attribute__((address_space(1))) void*)pa1,
                                         (__attribute__((address_space(3))) void*)&As[(w + 4) * 512], 16, 0, 0);
        __builtin_amdgcn_global_load_lds((const __attribute__((address_space(1))) void*)pb0,
                                         (__attribute__((address_space(3))) void*)&Bs[w * 512], 16, 0, 0);
        __builtin_amdgcn_global_load_lds((const __attribute__((address_space(1))) void*)pb1,
                                         (__attribute__((address_space(3))) void*)&Bs[(w + 4) * 512], 16, 0, 0);
        pa0 += 32; pa1 += 32; pb0 += 32; pb1 += 32;
        __syncthreads();
        bf16x8 af[4], bfr[4];
        #pragma unroll
        for (int m = 0; m < 4; ++m)
            af[m] = *reinterpret_cast<const bf16x8*>(&As[(wm * 4 + m) * 512 + lane * 8]);
        #pragma unroll
        for (int n = 0; n < 4; ++n)
            bfr[n] = *reinterpret_cast<const bf16x8*>(&Bs[(wn * 4 + n) * 512 + lane * 8]);
        #pragma unroll
        for (int m = 0; m < 4; ++m)
            #pragma unroll
            for (int n = 0; n < 4; ++n)
                acc[m][n] = __builtin_amdgcn_mfma_f32_16x16x32_bf16(af[m], bfr[n], acc[m][n], 0, 0, 0);
        __syncthreads();
    }

    const int rbase = bm + wm * 64;
    const int cbase = bn + wn * 64;
    #pragma unroll
    for (int m = 0; m < 4; ++m) {
        #pragma unroll
        for (int q = 0; q < 4; ++q) {
            int r = rbase + m * 16 + l4 * 4 + q;
            if (r >= M) continue;
            float rs = ROWSC ? rowsc[r] : 1.f;
            #pragma unroll
            for (int n = 0; n < 4; ++n) {
                int c = cbase + n * 16 + l15;
                float v = acc[m][n][q] + rs * bias[c];
                if (RELU) v = fmaxf(v, 0.f);
                if (!GUARDN || c < Nout) {
                    if (OUTF32) Cf[(long)r * Nout + c] = v;
                    else Cb[(long)r * Nout + c] = f2b(v);
                }
            }
        }
    }
}

// ---------------- column mean ----------------
__global__ __launch_bounds__(256) void col_mean(const float* __restrict__ y,
                                                float* __restrict__ mean_x,
                                                int rows, int cols) {
    int j = blockIdx.x;
    float s = 0.f;
    for (int i = threadIdx.x; i < rows; i += blockDim.x) s += y[(long)i * cols + j];
    __shared__ float red[256];
    red[threadIdx.x] = s;
    __syncthreads();
    for (int o = 128; o > 0; o >>= 1) {
        if (threadIdx.x < o) red[threadIdx.x] += red[threadIdx.x + o];
        __syncthreads();
    }
    if (threadIdx.x == 0) mean_x[j] = red[0] / (float)rows;
}

// ---------------- reg loss ----------------
__global__ __launch_bounds__(256) void reg_loss_k(const float* __restrict__ h,
                                                  const float* __restrict__ u_sum,
                                                  const float* __restrict__ mean_x,
                                                  float* __restrict__ acc,
                                                  int rows, int cols, float inv_n3) {
    long total = (long)rows * cols;
    long idx = (long)blockIdx.x * blockDim.x + threadIdx.x;
    long stride = (long)gridDim.x * blockDim.x;
    float s = 0.f;
    for (long t = idx; t < total; t += stride) {
        int i = (int)(t / cols);
        int j = (int)(t - (long)i * cols);
        float mu = u_sum[i] * inv_n3;
        float d = mu * h[t] - mean_x[j];
        s += d * d;
    }
    __shared__ float red[256];
    red[threadIdx.x] = s;
    __syncthreads();
    for (int o = 128; o > 0; o >>= 1) {
        if (threadIdx.x < o) red[threadIdx.x] += red[threadIdx.x + o];
        __syncthreads();
    }
    if (threadIdx.x == 0) atomicAdd(acc, red[0]);
}

__global__ void finalize_k(float* __restrict__ out, const float* __restrict__ acc, float scale) {
    if (threadIdx.x == 0) *out = *acc * scale;
}

extern "C" void kernel_launch(void* const* d_in, const int* in_sizes, int n_in,
                              void* d_out, int out_size, void* d_ws, size_t ws_size,
                              hipStream_t stream) {
    const float* x   = (const float*)d_in[0];
    const float* W1  = (const float*)d_in[1];
    const float* b1  = (const float*)d_in[2];
    const float* W2  = (const float*)d_in[3];
    const float* b2  = (const float*)d_in[4];
    const float* W3  = (const float*)d_in[5];
    const float* b3  = (const float*)d_in[6];
    const float* ew1 = (const float*)d_in[7];
    const float* ew2 = (const float*)d_in[8];
    const float* ew3 = (const float*)d_in[9];
    const float* u_sum = (const float*)d_in[10];
    const int* s1 = (const int*)d_in[11];
    const int* d1 = (const int*)d_in[12];
    const int* s2 = (const int*)d_in[13];
    const int* d2 = (const int*)d_in[14];
    const int* s3 = (const int*)d_in[15];
    const int* d3 = (const int*)d_in[16];

    const int K  = 256;
    const int n0 = in_sizes[0] / K;          // 100000
    const int E1 = in_sizes[7];              // 800000
    const int E2 = in_sizes[8];              // 400000
    const int E3 = in_sizes[9];              // 200000
    const int n2 = in_sizes[10];             // 25000
    const int NC = in_sizes[5] / K;          // 47
    const int n3 = (out_size - 1) / NC;      // 12500
    const int n1 = 50000;                    // fixed by problem

    const int NT = n1 + n2 + n3;             // concatenated dst count
    const int Et = E1 + E2 + E3;
    const int nb = (NT + 1023) / 1024;

    // ---- workspace layout ----
    float* ws = (float*)d_ws;
    long o = 0;
    auto take = [&](long words) { float* p = ws + o; o += (words + 3) & ~3L; return p; };
    int*    off  = (int*)take(NT + 1);
    int*    cur  = (int*)take(NT);
    int*    cnt  = (int*)take(NT);           // cnt+rw contiguous for one zero pass
    float*  rw   = take(n1 + n2);
    int*    bsum = (int*)take(nb);
    int*    bbase= (int*)take(nb);
    int2*   csr  = (int2*)take(2L * Et);
    ushort* Wt1b = (ushort*)take(256 * 256 / 2);
    ushort* Wt2b = (ushort*)take(256 * 256 / 2);
    ushort* Wt3b = (ushort*)take(128 * 256 / 2);
    float*  b3p  = take(128);
    ushort* aggb = (ushort*)take((long)n1 * 256 / 2);   // agg1 (n1) then agg2 (n2)
    ushort* xb   = (ushort*)take((long)n0 * 256 / 2);   // xb; later y1b + y2b
    float*  h3   = take((long)n2 * NC);
    float*  mean_x = take(64);
    float*  accs   = take(4);

    ushort* y1b = xb;                                   // [n1][256] (xb dead after gather1)
    ushort* y2b = xb + (long)n1 * 256;                  // [n2][256]
    float*  rw1 = rw;
    float*  rw2 = rw + n1;

    float* y3   = (float*)d_out;                        // [n3, NC]
    float* loss = y3 + (long)n3 * NC;

    dim3 blk(256);

    // ---- conversions (1+1 launches) ----
    f2b_k<<<dim3(2048), blk, 0, stream>>>(x, xb, (long)n0 * 256 / 8);
    wtrans_all<<<dim3(256), dim3(640), 0, stream>>>(W1, W2, W3, b3, Wt1b, Wt2b, Wt3b, b3p, NC);

    // ---- fused CSR build ----
    zero_i<<<dim3(128), blk, 0, stream>>>(cnt, NT + n1 + n2);  // cnt + rw contiguous
    hist_fused<<<dim3(2048), blk, 0, stream>>>(d1, d2, d3, ew1, ew2, E1, E2, E3, n1, n2, cnt, rw);
    scan1<<<dim3(nb), dim3(1024), 0, stream>>>(cnt, off, bsum, NT);
    scan2<<<dim3(1), dim3(128), 0, stream>>>(bsum, bbase, nb, &off[NT], accs);
    scan3<<<dim3(128), blk, 0, stream>>>(off, cur, bbase, NT);
    fill_fused<<<dim3(2048), blk, 0, stream>>>(s1, d1, s2, d2, s3, d3, ew1, ew2, ew3,
                                               E1, E2, E3, n1, n2, cur, csr);

    // ---- layer 1: agg1 = S1@xb ; y1b = relu(agg1@W1 + rw1⊗b1) ----
    gather_b4<<<dim3((n1 + 3) / 4), blk, 0, stream>>>(xb, off, csr, aggb, n1);
    gemm_mfma<true, false, true, false><<<dim3((n1 + 127) / 128, 2), blk, 0, stream>>>(
        aggb, Wt1b, b1, rw1, y1b, nullptr, n1, 256, K);

    // ---- layer 2: agg2 = S2@y1b ; y2b = relu(agg2@W2 + rw2⊗b2) ----
    gather_b4<<<dim3((n2 + 3) / 4), blk, 0, stream>>>(y1b, off + n1, csr, aggb, n2);
    gemm_mfma<true, false, true, false><<<dim3((n2 + 127) / 128, 2), blk, 0, stream>>>(
        aggb, Wt2b, b2, rw2, y2b, nullptr, n2, 256, K);

    // ---- layer 3: h3 = y2b@W3 + b3 (MFMA, padded to 128 cols) ; y3 = S3@h3 ----
    gemm_mfma<false, true, false, true><<<dim3((n2 + 127) / 128, 1), blk, 0, stream>>>(
        y2b, Wt3b, b3p, nullptr, nullptr, h3, n2, NC, K);
    gather_small<<<dim3((n3 + 3) / 4), blk, 0, stream>>>(h3, off + n1 + n2, csr, y3, n3, NC);

    // ---- reg loss ----
    col_mean<<<dim3(NC), blk, 0, stream>>>(y3, mean_x, n3, NC);
    reg_loss_k<<<dim3(512), blk, 0, stream>>>(h3, u_sum, mean_x, accs, n2, NC, 1.0f / (float)n3);
    finalize_k<<<dim3(1), dim3(1), 0, stream>>>(loss, accs, 1.0f / ((float)n2 * (float)NC));
}